// Round 8
// baseline (121.119 us; speedup 1.0000x reference)
//
#include <hip/hip_runtime.h>
#include <math.h>

#define CLS   4096      // row length C
#define KSEL  2048u     // k = round(C * 0.5)
#define TPB   256
#define ROWS  8         // rows per block, software-pipelined

typedef float f32x4 __attribute__((ext_vector_type(4)));

// LDS layout (bytes):
//  h0   : u32[2][2052] @     0 (16416)  pass0 hist, 12-bit bins, 2 copies, permuted slots
//  cand : u32[512]     @ 16416 ( 2048)  boundary-bin candidates (packed keys)
//         ALIAS (cnt>512 fallback only): h1 u32[260] @16416, h2 u32[260] @17456, h3 u32[64] @18496
//  s_cnt u32 @18752 ; s_wt u32[4] @18756 ; s_bc u32[3] @18772 ; s_fr f32[8] @18784 -> 18816
//  tie-path aliases (h0 dead): s_flag u8[4096] @0 ; s_suf u32[256] @8192
//  zero-per-row region = [0, 18464) = 1154 uint4 (+ s_cnt), done in epilogue shadow

__device__ __forceinline__ int h0slot(unsigned b) {
    unsigned j = b & 7u, t = b >> 3;
    return (int)((j << 8) | ((t + 4u*j) & 255u));
}

template<int SHIFT, int NBITS, int BPL>
__device__ __forceinline__ void radix_small(const float sc[16], unsigned* hist,
        int lane, unsigned& prefix, unsigned& kr, unsigned& cnt_eq)
{
    const unsigned msk = (1u << NBITS) - 1u;
    #pragma unroll
    for (int i = 0; i < 16; ++i) {
        unsigned u = __float_as_uint(sc[i]);
        if ((u >> (SHIFT + NBITS)) == (prefix >> (SHIFT + NBITS)))
            atomicAdd(&hist[(u >> SHIFT) & msk], 1u);
    }
    __syncthreads();
    unsigned c[BPL];
    if constexpr (BPL == 4) {
        uint4 x = *(const uint4*)&hist[lane * 4];
        c[0] = x.x; c[1] = x.y; c[2] = x.z; c[3] = x.w;
    } else {
        c[0] = hist[lane];
    }
    unsigned sfx[BPL + 1]; sfx[BPL] = 0;
    #pragma unroll
    for (int j = BPL - 1; j >= 0; --j) sfx[j] = sfx[j + 1] + c[j];
    const unsigned tot = sfx[0];
    unsigned s = tot;
    #pragma unroll
    for (int off = 1; off < 64; off <<= 1) {
        unsigned t = __shfl_down(s, off);
        if (lane + off < 64) s += t;
    }
    const unsigned Sx = s - tot;
    const bool has = (Sx < kr) && (kr <= Sx + tot);
    unsigned bin = 0, below = 0, ceq = 0;
    if (has) {
        #pragma unroll
        for (int j = 0; j < BPL; ++j)
            if (Sx + sfx[j] >= kr && Sx + sfx[j + 1] < kr) {
                bin = (unsigned)(lane * BPL + j);
                below = Sx + sfx[j + 1];
                ceq = c[j];
            }
    }
    unsigned long long m = __ballot(has);
    int src = (int)__builtin_ctzll(m);
    bin = __shfl(bin, src); below = __shfl(below, src); ceq = __shfl(ceq, src);
    prefix |= bin << SHIFT;
    kr -= below;
    cnt_eq = ceq;
}

__global__ __launch_bounds__(TPB) void proxy_gate_kernel(
    const float* __restrict__ token,
    const float* __restrict__ proxy,
    float* __restrict__ out,
    int nrows)
{
    __shared__ __align__(16) unsigned char lds[18816];
    unsigned* h0    = (unsigned*)(lds);
    unsigned* cand  = (unsigned*)(lds + 16416);
    unsigned* h1    = (unsigned*)(lds + 16416);
    unsigned* h2    = (unsigned*)(lds + 17456);
    unsigned* h3    = (unsigned*)(lds + 18496);
    unsigned* s_cnt = (unsigned*)(lds + 18752);
    unsigned* s_wt  = (unsigned*)(lds + 18756);
    unsigned* s_bc  = (unsigned*)(lds + 18772);
    float*    s_fr  = (float*)   (lds + 18784);
    unsigned char* s_flag = lds;                    // alias: h0 dead after scan
    unsigned*      s_suf  = (unsigned*)(lds + 8192);

    const int tid  = threadIdx.x;
    const int lane = tid & 63;
    const int wv   = tid >> 6;
    const int row0 = blockIdx.x * ROWS;

    // ---- prologue: issue row0 loads; zero LDS under their latency ----
    float4 tv[4], pv[4];
    {
        const float4* t4 = (const float4*)(token + (size_t)row0 * CLS);
        const float4* p4 = (const float4*)(proxy + (size_t)row0 * CLS);
        #pragma unroll
        for (int i = 0; i < 4; ++i) { tv[i] = t4[i*TPB + tid]; pv[i] = p4[i*TPB + tid]; }
    }
    {
        uint4 z = make_uint4(0u, 0u, 0u, 0u);
        uint4* zp = (uint4*)lds;
        #pragma unroll
        for (int m = 0; m < 5; ++m) { int idx = m*TPB + tid; if (idx < 1154) zp[idx] = z; }
        if (tid == 0) *s_cnt = 0u;
    }

    for (int r = 0; r < ROWS; ++r) {
        const int row = row0 + r;
        if (row >= nrows) break;
        const bool pf = (r + 1 < ROWS) && (row + 1 < nrows);

        // ---- issue NEXT row's loads first: their latency hides under this
        //      row's entire selection chain ----
        float4 ntv[4], npv[4];
        if (pf) {
            const float4* t4 = (const float4*)(token + (size_t)(row+1) * CLS);
            const float4* p4 = (const float4*)(proxy + (size_t)(row+1) * CLS);
            #pragma unroll
            for (int i = 0; i < 4; ++i) { ntv[i] = t4[i*TPB + tid]; npv[i] = p4[i*TPB + tid]; }
        }

        // ---- scores + stats partials (tv stays live as token values) ----
        float sc[16];
        float sum = 0.f, sumsq = 0.f;
        #pragma unroll
        for (int i = 0; i < 4; ++i) {
            float a;
            a = fabsf(tv[i].x*pv[i].x); sc[i*4+0]=a; sum+=a; sumsq+=a*a;
            a = fabsf(tv[i].y*pv[i].y); sc[i*4+1]=a; sum+=a; sumsq+=a*a;
            a = fabsf(tv[i].z*pv[i].z); sc[i*4+2]=a; sum+=a; sumsq+=a*a;
            a = fabsf(tv[i].w*pv[i].w); sc[i*4+3]=a; sum+=a; sumsq+=a*a;
        }
        __syncthreads();                             // B0: LDS zeroing visible

        // ---- pass 0 atomics (12-bit bins, permuted slots) + stats reduce ----
        {
            unsigned* h0c = h0 + (((tid >> 2) & 1) ? 2052 : 0);
            #pragma unroll
            for (int i = 0; i < 16; ++i)
                atomicAdd(&h0c[h0slot(__float_as_uint(sc[i]) >> 20)], 1u);
        }
        #pragma unroll
        for (int off = 32; off > 0; off >>= 1) {
            sum   += __shfl_xor(sum, off);
            sumsq += __shfl_xor(sumsq, off);
        }
        if (lane == 0) { s_fr[wv] = sum; s_fr[4+wv] = sumsq; }
        __syncthreads();                             // B1

        const float tot_s = s_fr[0]+s_fr[1]+s_fr[2]+s_fr[3];
        const float tot_q = s_fr[4]+s_fr[5]+s_fr[6]+s_fr[7];
        const float mu = tot_s * (1.0f/CLS);
        float var = (tot_q - tot_s*mu) * (1.0f/(CLS-1));
        var = fmaxf(var, 0.0f);
        const float inv_sigma = 1.0f / fmaxf(sqrtf(var), 1e-6f);

        // ---- pass 0 scan: thread t owns bins [8t,8t+8), conflict-free reads ----
        unsigned kr = KSEL;
        {
            unsigned c[8];
            #pragma unroll
            for (int j = 0; j < 8; ++j) {
                int sl = (j << 8) | ((tid + 4*j) & 255);
                c[j] = h0[sl] + h0[2052 + sl];
            }
            unsigned sfx[9]; sfx[8] = 0;
            #pragma unroll
            for (int j = 7; j >= 0; --j) sfx[j] = sfx[j+1] + c[j];
            const unsigned tot = sfx[0];
            unsigned s = tot;
            #pragma unroll
            for (int off = 1; off < 64; off <<= 1) {
                unsigned t = __shfl_down(s, off);
                if (lane + off < 64) s += t;
            }
            if (lane == 0) s_wt[wv] = s;
            __syncthreads();                         // B2
            unsigned addhi = 0;
            #pragma unroll
            for (int w2 = 0; w2 < 4; ++w2) if (w2 > wv) addhi += s_wt[w2];
            const unsigned Sx = (s - tot) + addhi;
            if (Sx < kr && kr <= Sx + tot) {
                #pragma unroll
                for (int j = 0; j < 8; ++j)
                    if (Sx + sfx[j] >= kr && Sx + sfx[j+1] < kr) {
                        s_bc[0] = (unsigned)(tid*8 + j);
                        s_bc[1] = Sx + sfx[j+1];
                        s_bc[2] = c[j];
                    }
            }
            __syncthreads();                         // B3
            kr -= s_bc[1];
        }
        const unsigned bin = s_bc[0];
        unsigned cnt_eq = s_bc[2];

        // ---- gather boundary-bin candidates: key=(low20<<12)|(4095-idx) ----
        {
            unsigned cmask = 0, lc = 0;
            #pragma unroll
            for (int ii = 0; ii < 16; ++ii) {
                bool cnd = ((__float_as_uint(sc[ii]) >> 20) == bin);
                cmask |= ((unsigned)cnd) << ii;
                lc += (unsigned)cnd;
            }
            unsigned inc = lc;
            #pragma unroll
            for (int off = 1; off < 64; off <<= 1) {
                unsigned t = __shfl_up(inc, off);
                if (lane >= off) inc += t;
            }
            const unsigned wtot = __shfl(inc, 63);
            unsigned wbase = 0;
            if (lane == 0) wbase = atomicAdd(s_cnt, wtot);
            wbase = __shfl(wbase, 0);
            unsigned p = wbase + (inc - lc);
            #pragma unroll
            for (int ii = 0; ii < 16; ++ii) {
                if ((cmask >> ii) & 1u) {
                    unsigned u = __float_as_uint(sc[ii]);
                    unsigned idx = (unsigned)((ii >> 2)*1024 + tid*4 + (ii & 3));
                    if (p < 512u) cand[p] = ((u & 0xFFFFFu) << 12) | (4095u - idx);
                    ++p;
                }
            }
        }
        __syncthreads();                             // B4
        const unsigned cnt = *s_cnt;
        const bool cand_mode = (cnt <= 512u);

        float thr = 0.f; bool tie_rare = false;
        if (cand_mode) {
            // ---- cooperative rank: thread handles cand slots tid, tid+256 ----
            #pragma unroll
            for (int rpt = 0; rpt < 2; ++rpt) {
                const unsigned slot = (unsigned)tid + (unsigned)rpt*256u;
                if (slot < cnt) {
                    const unsigned my = cand[slot];
                    unsigned rank = 0;
                    const uint4* c4 = (const uint4*)cand;
                    const unsigned nq = (cnt + 3u) >> 2;
                    for (unsigned q = 0; q < nq; ++q) {
                        uint4 v = c4[q];
                        rank += (unsigned)(v.x > my) + (unsigned)(v.y > my)
                              + (unsigned)(v.z > my) + (unsigned)(v.w > my);
                    }
                    if (rank == kr - 1u) s_bc[0] = my;
                }
            }
        } else {
            // ---- rare fallback (cnt>512): radix chain + stable tie ranking ----
            unsigned prefix = bin << 20;
            {
                unsigned* hz = (unsigned*)(lds + 16416);
                #pragma unroll
                for (int m = 0; m < 3; ++m) { int ix = m*TPB + tid; if (ix < 584) hz[ix] = 0u; }
            }
            __syncthreads();
            radix_small<12, 8, 4>(sc, h1, lane, prefix, kr, cnt_eq);
            radix_small< 4, 8, 4>(sc, h2, lane, prefix, kr, cnt_eq);
            radix_small< 0, 4, 1>(sc, h3, lane, prefix, kr, cnt_eq);
            thr = __uint_as_float(prefix);
            tie_rare = (cnt_eq != kr);
            if (tie_rare) {
                #pragma unroll
                for (int i = 0; i < 4; ++i)
                    #pragma unroll
                    for (int c2 = 0; c2 < 4; ++c2)
                        s_flag[i*1024 + tid*4 + c2] = (sc[i*4+c2] == thr) ? 1 : 0;
                __syncthreads();
                unsigned lc = 0;
                unsigned char mf[16];
                #pragma unroll
                for (int m = 0; m < 16; ++m) { mf[m] = s_flag[tid*16 + m]; lc += mf[m]; }
                s_suf[tid] = lc;
                __syncthreads();
                #pragma unroll
                for (int off = 1; off < 256; off <<= 1) {
                    unsigned w = s_suf[tid] + ((tid >= off) ? s_suf[tid - off] : 0u);
                    __syncthreads();
                    s_suf[tid] = w;
                    __syncthreads();
                }
                unsigned r2 = s_suf[tid] - lc;
                #pragma unroll
                for (int m = 0; m < 16; ++m) {
                    if (mf[m]) { s_flag[tid*16 + m] = (r2 < kr) ? 2 : 0; ++r2; }
                }
            }
        }
        __syncthreads();                             // B5: Kthresh / flags visible
        const unsigned Kth = s_bc[0];

        // ---- gate + store row r ----
        f32x4* o4 = (f32x4*)(out + (size_t)row * CLS);
        #pragma unroll
        for (int i = 0; i < 4; ++i) {
            const float tkc[4] = { tv[i].x, tv[i].y, tv[i].z, tv[i].w };
            f32x4 rv;
            #pragma unroll
            for (int c2 = 0; c2 < 4; ++c2) {
                const float s = sc[i*4+c2];
                const float z = (s - mu) * inv_sigma;
                const float soft = 1.0f / (1.0f + __expf(-z));
                bool hard;
                const unsigned u = __float_as_uint(s);
                if (cand_mode) {
                    const unsigned e = u >> 20;
                    const unsigned idx = (unsigned)(i*1024 + tid*4 + c2);
                    const unsigned packed = ((u & 0xFFFFFu) << 12) | (4095u - idx);
                    hard = (e > bin) || ((e == bin) && (packed >= Kth));
                } else if (tie_rare) {
                    hard = (s > thr) || ((s == thr) && (s_flag[i*1024 + tid*4 + c2] == 2));
                } else {
                    hard = (s >= thr);
                }
                rv[c2] = tkc[c2] * (hard ? 1.0f : soft);
            }
            __builtin_nontemporal_store(rv, &o4[i*TPB + tid]);
        }

        if (!cand_mode) __syncthreads();             // rare: protect s_flag reads

        // ---- zero LDS for next row in the epilogue shadow; B0' publishes ----
        if (pf) {
            uint4 z = make_uint4(0u, 0u, 0u, 0u);
            uint4* zp = (uint4*)lds;
            #pragma unroll
            for (int m = 0; m < 5; ++m) { int idx = m*TPB + tid; if (idx < 1154) zp[idx] = z; }
            if (tid == 0) *s_cnt = 0u;
            #pragma unroll
            for (int i = 0; i < 4; ++i) { tv[i] = ntv[i]; pv[i] = npv[i]; }
        }
    }
}

extern "C" void kernel_launch(void* const* d_in, const int* in_sizes, int n_in,
                              void* d_out, int out_size, void* d_ws, size_t ws_size,
                              hipStream_t stream) {
    const float* token = (const float*)d_in[0];
    const float* proxy = (const float*)d_in[1];
    float* outp = (float*)d_out;
    const int B = in_sizes[0] / CLS;
    const int nblk = (B + ROWS - 1) / ROWS;
    hipLaunchKernelGGL(proxy_gate_kernel, dim3(nblk), dim3(TPB), 0, stream,
                       token, proxy, outp, B);
}

// Round 9
// 102.707 us; speedup vs baseline: 1.1793x; 1.1793x over previous
//
#include <hip/hip_runtime.h>
#include <math.h>

#define CLS   4096      // row length C
#define KSEL  2048u     // k = round(C * 0.5)
#define TPB   256

typedef float f32x4 __attribute__((ext_vector_type(4)));

// LDS layout (bytes):
//  h0   : u32[2][2048] @     0 (16384)  12-bit hist, plain layout, 2 copies
//  cand : u32[512]     @ 16384 ( 2048)  boundary-bin candidates (packed keys)
//  s_cnt u32 @18432 ; s_bcK u32 @18436 ; s_fr f32[8] @18448 -> 18480 total
//  fallback aliases (h0 dead after scan/gather):
//    h1 u32[260] @0 ; h2 u32[260] @1040 ; h3 u32[64] @2080 (end 2336)
//    s_flag u8[4096] @4096 ; s_suf u32[256] @8192
//  zero region = [0,18432) = 1152 uint4 + s_cnt, under global-load latency

template<int SHIFT, int NBITS, int BPL>
__device__ __forceinline__ void radix_small(const float sc[16], unsigned* hist,
        int lane, unsigned& prefix, unsigned& kr, unsigned& cnt_eq)
{
    const unsigned msk = (1u << NBITS) - 1u;
    #pragma unroll
    for (int i = 0; i < 16; ++i) {
        unsigned u = __float_as_uint(sc[i]);
        if ((u >> (SHIFT + NBITS)) == (prefix >> (SHIFT + NBITS)))
            atomicAdd(&hist[(u >> SHIFT) & msk], 1u);
    }
    __syncthreads();
    unsigned c[BPL];
    if constexpr (BPL == 4) {
        uint4 x = *(const uint4*)&hist[lane * 4];
        c[0] = x.x; c[1] = x.y; c[2] = x.z; c[3] = x.w;
    } else {
        c[0] = hist[lane];
    }
    unsigned sfx[BPL + 1]; sfx[BPL] = 0;
    #pragma unroll
    for (int j = BPL - 1; j >= 0; --j) sfx[j] = sfx[j + 1] + c[j];
    const unsigned tot = sfx[0];
    unsigned s = tot;
    #pragma unroll
    for (int off = 1; off < 64; off <<= 1) {
        unsigned t = __shfl_down(s, off);
        if (lane + off < 64) s += t;
    }
    const unsigned Sx = s - tot;
    const bool has = (Sx < kr) && (kr <= Sx + tot);
    unsigned bin = 0, below = 0, ceq = 0;
    if (has) {
        #pragma unroll
        for (int j = 0; j < BPL; ++j)
            if (Sx + sfx[j] >= kr && Sx + sfx[j + 1] < kr) {
                bin = (unsigned)(lane * BPL + j);
                below = Sx + sfx[j + 1];
                ceq = c[j];
            }
    }
    unsigned long long m = __ballot(has);
    int src = (int)__builtin_ctzll(m);
    bin = __shfl(bin, src); below = __shfl(below, src); ceq = __shfl(ceq, src);
    prefix |= bin << SHIFT;
    kr -= below;
    cnt_eq = ceq;
}

__global__ __launch_bounds__(TPB) void proxy_gate_kernel(
    const float* __restrict__ token,
    const float* __restrict__ proxy,
    float* __restrict__ out)
{
    __shared__ __align__(16) unsigned char lds[18480];
    unsigned* h0    = (unsigned*)(lds);
    unsigned* cand  = (unsigned*)(lds + 16384);
    unsigned* s_cnt = (unsigned*)(lds + 18432);
    unsigned* s_bcK = (unsigned*)(lds + 18436);
    float*    s_fr  = (float*)   (lds + 18448);
    unsigned* h1    = (unsigned*)(lds);           // fallback aliases (h0 dead)
    unsigned* h2    = (unsigned*)(lds + 1040);
    unsigned* h3    = (unsigned*)(lds + 2080);
    unsigned char* s_flag = lds + 4096;
    unsigned*      s_suf  = (unsigned*)(lds + 8192);

    const int tid  = threadIdx.x;
    const int lane = tid & 63;
    const int wv   = tid >> 6;
    const size_t base = (size_t)blockIdx.x * CLS;
    const float4* t4 = (const float4*)(token + base);
    const float4* p4 = (const float4*)(proxy + base);
    f32x4* o4 = (f32x4*)(out + base);

    // ---- issue all global loads; zero h0+cand (+s_cnt) under their latency ----
    float4 tv[4], pv[4];
    #pragma unroll
    for (int i = 0; i < 4; ++i) { tv[i] = t4[i*TPB + tid]; pv[i] = p4[i*TPB + tid]; }
    {
        uint4 z = make_uint4(0u, 0u, 0u, 0u);
        uint4* zp = (uint4*)lds;
        #pragma unroll
        for (int m = 0; m < 5; ++m) { int idx = m*TPB + tid; if (idx < 1152) zp[idx] = z; }
        if (tid == 0) *s_cnt = 0u;
    }

    float sc[16];
    float sum = 0.f, sumsq = 0.f;
    #pragma unroll
    for (int i = 0; i < 4; ++i) {
        float a;
        a = fabsf(tv[i].x*pv[i].x); sc[i*4+0]=a; sum+=a; sumsq+=a*a;
        a = fabsf(tv[i].y*pv[i].y); sc[i*4+1]=a; sum+=a; sumsq+=a*a;
        a = fabsf(tv[i].z*pv[i].z); sc[i*4+2]=a; sum+=a; sumsq+=a*a;
        a = fabsf(tv[i].w*pv[i].w); sc[i*4+3]=a; sum+=a; sumsq+=a*a;
    }
    __syncthreads();                                 // B0: zeroing visible

    // ---- pass 0 atomics (12-bit bins, 2 copies) + stats reduce ----
    {
        unsigned* h0c = h0 + (((tid >> 2) & 1) ? 2048 : 0);
        #pragma unroll
        for (int i = 0; i < 16; ++i)
            atomicAdd(&h0c[__float_as_uint(sc[i]) >> 20], 1u);
    }
    #pragma unroll
    for (int off = 32; off > 0; off >>= 1) {
        sum   += __shfl_xor(sum, off);
        sumsq += __shfl_xor(sumsq, off);
    }
    if (lane == 0) { s_fr[wv] = sum; s_fr[4+wv] = sumsq; }
    __syncthreads();                                 // B1: atomics + stats visible

    const float tot_s = s_fr[0]+s_fr[1]+s_fr[2]+s_fr[3];
    const float tot_q = s_fr[4]+s_fr[5]+s_fr[6]+s_fr[7];
    const float mu = tot_s * (1.0f/CLS);
    float var = (tot_q - tot_s*mu) * (1.0f/(CLS-1));
    var = fmaxf(var, 0.0f);
    const float inv_sigma = 1.0f / fmaxf(sqrtf(var), 1e-6f);

    // ---- wave-redundant scan: each wave reads the full histogram, finds the
    //      boundary bin in registers. NO barriers, no LDS broadcast. ----
    // lane owns logical bins [32*lane, 32*lane+32)
    unsigned kr = KSEL, bin = 0, cnt_eq = 0;
    {
        const uint4* h4 = (const uint4*)h0;          // copy1 at uint4 idx 512
        unsigned tot = 0;
        #pragma unroll
        for (int w = 0; w < 8; ++w) {
            uint4 a  = h4[lane*8 + w];
            uint4 b2 = h4[512 + lane*8 + w];
            tot += a.x+a.y+a.z+a.w + b2.x+b2.y+b2.z+b2.w;
        }
        unsigned s = tot;
        #pragma unroll
        for (int off = 1; off < 64; off <<= 1) {
            unsigned t = __shfl_down(s, off);
            if (lane + off < 64) s += t;
        }
        const unsigned Sx = s - tot;                 // count in bins above lane's range
        const bool has = (Sx < kr) && (kr <= Sx + tot);
        unsigned fbin = 0, fabove = 0, fceq = 0;
        if (has) {                                   // exactly one lane active
            unsigned r = Sx;
            for (int w = 7; w >= 0; --w) {
                uint4 a  = h4[lane*8 + w];
                uint4 b2 = h4[512 + lane*8 + w];
                unsigned cc[4] = { a.x+b2.x, a.y+b2.y, a.z+b2.z, a.w+b2.w };
                for (int u = 3; u >= 0; --u) {
                    unsigned rn = r + cc[u];
                    if (r < kr && kr <= rn) {
                        fbin = (unsigned)(lane*32 + w*4 + u);
                        fabove = r; fceq = cc[u];
                    }
                    r = rn;
                }
            }
        }
        unsigned long long m = __ballot(has);
        int src = (int)__builtin_ctzll(m);
        bin    = __shfl(fbin, src);
        kr    -= __shfl(fabove, src);
        cnt_eq = __shfl(fceq, src);
    }

    // ---- gather boundary-bin candidates: key=(low20<<12)|(4095-idx), distinct ----
    {
        unsigned cmask = 0, lc = 0;
        #pragma unroll
        for (int ii = 0; ii < 16; ++ii) {
            bool cnd = ((__float_as_uint(sc[ii]) >> 20) == bin);
            cmask |= ((unsigned)cnd) << ii;
            lc += (unsigned)cnd;
        }
        unsigned inc = lc;
        #pragma unroll
        for (int off = 1; off < 64; off <<= 1) {
            unsigned t = __shfl_up(inc, off);
            if (lane >= off) inc += t;
        }
        const unsigned wtot = __shfl(inc, 63);
        unsigned wbase = 0;
        if (lane == 0) wbase = atomicAdd(s_cnt, wtot);
        wbase = __shfl(wbase, 0);
        unsigned p = wbase + (inc - lc);
        #pragma unroll
        for (int ii = 0; ii < 16; ++ii) {
            if ((cmask >> ii) & 1u) {
                unsigned u = __float_as_uint(sc[ii]);
                unsigned idx = (unsigned)((ii >> 2)*1024 + tid*4 + (ii & 3));
                if (p < 512u) cand[p] = ((u & 0xFFFFFu) << 12) | (4095u - idx);
                ++p;
            }
        }
    }
    __syncthreads();                                 // B4
    const unsigned cnt = *s_cnt;
    const bool cand_mode = (cnt <= 512u);

    float thr = 0.f; bool tie_rare = false;
    if (cand_mode) {
        // ---- cooperative rank: thread handles cand slots tid, tid+256 ----
        #pragma unroll
        for (int rpt = 0; rpt < 2; ++rpt) {
            const unsigned slot = (unsigned)tid + (unsigned)rpt*256u;
            if (slot < cnt) {
                const unsigned my = cand[slot];
                unsigned rank = 0;
                const uint4* c4 = (const uint4*)cand;
                const unsigned nq = (cnt + 3u) >> 2;
                for (unsigned q = 0; q < nq; ++q) {  // same-address broadcast reads
                    uint4 v = c4[q];
                    rank += (unsigned)(v.x > my) + (unsigned)(v.y > my)
                          + (unsigned)(v.z > my) + (unsigned)(v.w > my);
                }
                if (rank == kr - 1u) *s_bcK = my;    // unique: keys distinct
            }
        }
    } else {
        // ---- rare fallback (cnt>512): radix chain + stable tie ranking ----
        unsigned prefix = bin << 20;
        {
            unsigned* hz = (unsigned*)lds;           // zero h1/h2/h3 (h0 dead)
            #pragma unroll
            for (int m = 0; m < 3; ++m) { int ix = m*TPB + tid; if (ix < 584) hz[ix] = 0u; }
        }
        __syncthreads();
        radix_small<12, 8, 4>(sc, h1, lane, prefix, kr, cnt_eq);
        radix_small< 4, 8, 4>(sc, h2, lane, prefix, kr, cnt_eq);
        radix_small< 0, 4, 1>(sc, h3, lane, prefix, kr, cnt_eq);
        thr = __uint_as_float(prefix);
        tie_rare = (cnt_eq != kr);
        if (tie_rare) {
            #pragma unroll
            for (int i = 0; i < 4; ++i)
                #pragma unroll
                for (int c2 = 0; c2 < 4; ++c2)
                    s_flag[i*1024 + tid*4 + c2] = (sc[i*4+c2] == thr) ? 1 : 0;
            __syncthreads();
            unsigned lc = 0;
            unsigned char mf[16];
            #pragma unroll
            for (int m = 0; m < 16; ++m) { mf[m] = s_flag[tid*16 + m]; lc += mf[m]; }
            s_suf[tid] = lc;
            __syncthreads();
            #pragma unroll
            for (int off = 1; off < 256; off <<= 1) {
                unsigned w = s_suf[tid] + ((tid >= off) ? s_suf[tid - off] : 0u);
                __syncthreads();
                s_suf[tid] = w;
                __syncthreads();
            }
            unsigned r2 = s_suf[tid] - lc;
            #pragma unroll
            for (int m = 0; m < 16; ++m) {
                if (mf[m]) { s_flag[tid*16 + m] = (r2 < kr) ? 2 : 0; ++r2; }
            }
        }
    }
    __syncthreads();                                 // B5: Kth / flags visible
    const unsigned Kth = *s_bcK;

    // ---- gate + store (tv/sc still in registers) ----
    #pragma unroll
    for (int i = 0; i < 4; ++i) {
        const float tkc[4] = { tv[i].x, tv[i].y, tv[i].z, tv[i].w };
        f32x4 rv;
        #pragma unroll
        for (int c2 = 0; c2 < 4; ++c2) {
            const float s = sc[i*4+c2];
            const float z = (s - mu) * inv_sigma;
            const float soft = 1.0f / (1.0f + __expf(-z));
            bool hard;
            const unsigned u = __float_as_uint(s);
            if (cand_mode) {
                const unsigned e = u >> 20;
                const unsigned idx = (unsigned)(i*1024 + tid*4 + c2);
                const unsigned packed = ((u & 0xFFFFFu) << 12) | (4095u - idx);
                hard = (e > bin) || ((e == bin) && (packed >= Kth));
            } else if (tie_rare) {
                hard = (s > thr) || ((s == thr) && (s_flag[i*1024 + tid*4 + c2] == 2));
            } else {
                hard = (s >= thr);
            }
            rv[c2] = tkc[c2] * (hard ? 1.0f : soft);
        }
        __builtin_nontemporal_store(rv, &o4[i*TPB + tid]);
    }
}

extern "C" void kernel_launch(void* const* d_in, const int* in_sizes, int n_in,
                              void* d_out, int out_size, void* d_ws, size_t ws_size,
                              hipStream_t stream) {
    const float* token = (const float*)d_in[0];
    const float* proxy = (const float*)d_in[1];
    float* outp = (float*)d_out;
    const int B = in_sizes[0] / CLS;
    hipLaunchKernelGGL(proxy_gate_kernel, dim3(B), dim3(TPB), 0, stream,
                       token, proxy, outp);
}

// Round 10
// 67.539 us; speedup vs baseline: 1.7933x; 1.5207x over previous
//
#include <hip/hip_runtime.h>
#include <math.h>

#define CLS   4096      // row length C
#define KSEL  2048u     // k = round(C * 0.5)
#define TPB   256

typedef float f32x4 __attribute__((ext_vector_type(4)));

// LDS layout (bytes), total 10304:
//  h0   : u32[2048] @     0 ( 8192)  12-bit hist, single copy, plain layout
//  cand : u32[512]  @  8192 ( 2048)  boundary-bin candidates (packed keys)
//  s_cnt u32 @10240 ; s_wt u32[4] @10244 ; s_bc u32[3] @10260 ; s_fr f32[8] @10272
//  zero region = [0,10240) = 640 uint4 (+s_cnt), under global-load latency
//  fallback aliases (h0/cand dead): s_flag u8[4096]@0 ; s_suf u32[256]@4096 ;
//    h1 u32[260]@5120 ; h2 u32[260]@6160 ; h3 u32[64]@7200

template<int SHIFT, int NBITS, int BPL>
__device__ __forceinline__ void radix_small(const float sc[16], unsigned* hist,
        int lane, unsigned& prefix, unsigned& kr, unsigned& cnt_eq)
{
    const unsigned msk = (1u << NBITS) - 1u;
    #pragma unroll
    for (int i = 0; i < 16; ++i) {
        unsigned u = __float_as_uint(sc[i]);
        if ((u >> (SHIFT + NBITS)) == (prefix >> (SHIFT + NBITS)))
            atomicAdd(&hist[(u >> SHIFT) & msk], 1u);
    }
    __syncthreads();
    unsigned c[BPL];
    if constexpr (BPL == 4) {
        uint4 x = *(const uint4*)&hist[lane * 4];
        c[0] = x.x; c[1] = x.y; c[2] = x.z; c[3] = x.w;
    } else {
        c[0] = hist[lane];
    }
    unsigned sfx[BPL + 1]; sfx[BPL] = 0;
    #pragma unroll
    for (int j = BPL - 1; j >= 0; --j) sfx[j] = sfx[j + 1] + c[j];
    const unsigned tot = sfx[0];
    unsigned s = tot;
    #pragma unroll
    for (int off = 1; off < 64; off <<= 1) {
        unsigned t = __shfl_down(s, off);
        if (lane + off < 64) s += t;
    }
    const unsigned Sx = s - tot;
    const bool has = (Sx < kr) && (kr <= Sx + tot);
    unsigned bin = 0, below = 0, ceq = 0;
    if (has) {
        #pragma unroll
        for (int j = 0; j < BPL; ++j)
            if (Sx + sfx[j] >= kr && Sx + sfx[j + 1] < kr) {
                bin = (unsigned)(lane * BPL + j);
                below = Sx + sfx[j + 1];
                ceq = c[j];
            }
    }
    unsigned long long m = __ballot(has);
    int src = (int)__builtin_ctzll(m);
    bin = __shfl(bin, src); below = __shfl(below, src); ceq = __shfl(ceq, src);
    prefix |= bin << SHIFT;
    kr -= below;
    cnt_eq = ceq;
}

__global__ __launch_bounds__(TPB) void proxy_gate_kernel(
    const float* __restrict__ token,
    const float* __restrict__ proxy,
    float* __restrict__ out)
{
    __shared__ __align__(16) unsigned char lds[10304];
    unsigned* h0    = (unsigned*)(lds);
    unsigned* cand  = (unsigned*)(lds + 8192);
    unsigned* s_cnt = (unsigned*)(lds + 10240);
    unsigned* s_wt  = (unsigned*)(lds + 10244);
    unsigned* s_bc  = (unsigned*)(lds + 10260);
    float*    s_fr  = (float*)   (lds + 10272);
    unsigned char* s_flag = lds;                    // fallback aliases (h0 dead)
    unsigned*      s_suf  = (unsigned*)(lds + 4096);
    unsigned*      h1     = (unsigned*)(lds + 5120);
    unsigned*      h2     = (unsigned*)(lds + 6160);
    unsigned*      h3     = (unsigned*)(lds + 7200);

    const int tid  = threadIdx.x;
    const int lane = tid & 63;
    const int wv   = tid >> 6;
    const size_t base = (size_t)blockIdx.x * CLS;
    const float4* t4 = (const float4*)(token + base);
    const float4* p4 = (const float4*)(proxy + base);
    f32x4* o4 = (f32x4*)(out + base);

    // ---- issue all global loads; zero h0+cand (+s_cnt) under their latency ----
    float4 tv[4], pv[4];
    #pragma unroll
    for (int i = 0; i < 4; ++i) { tv[i] = t4[i*TPB + tid]; pv[i] = p4[i*TPB + tid]; }
    {
        uint4 z = make_uint4(0u, 0u, 0u, 0u);
        uint4* zp = (uint4*)lds;
        #pragma unroll
        for (int m = 0; m < 3; ++m) { int idx = m*TPB + tid; if (idx < 640) zp[idx] = z; }
        if (tid == 0) *s_cnt = 0u;
    }

    float sc[16];
    float sum = 0.f, sumsq = 0.f;
    #pragma unroll
    for (int i = 0; i < 4; ++i) {
        float a;
        a = fabsf(tv[i].x*pv[i].x); sc[i*4+0]=a; sum+=a; sumsq+=a*a;
        a = fabsf(tv[i].y*pv[i].y); sc[i*4+1]=a; sum+=a; sumsq+=a*a;
        a = fabsf(tv[i].z*pv[i].z); sc[i*4+2]=a; sum+=a; sumsq+=a*a;
        a = fabsf(tv[i].w*pv[i].w); sc[i*4+3]=a; sum+=a; sumsq+=a*a;
    }
    __syncthreads();                                 // B0: zeroing visible

    // ---- pass 0 atomics (12-bit bins, single copy, plain addr) + stats ----
    #pragma unroll
    for (int i = 0; i < 16; ++i)
        atomicAdd(&h0[__float_as_uint(sc[i]) >> 20], 1u);
    #pragma unroll
    for (int off = 32; off > 0; off >>= 1) {
        sum   += __shfl_xor(sum, off);
        sumsq += __shfl_xor(sumsq, off);
    }
    if (lane == 0) { s_fr[wv] = sum; s_fr[4+wv] = sumsq; }
    __syncthreads();                                 // B1: atomics + stats visible

    const float tot_s = s_fr[0]+s_fr[1]+s_fr[2]+s_fr[3];
    const float tot_q = s_fr[4]+s_fr[5]+s_fr[6]+s_fr[7];
    const float mu = tot_s * (1.0f/CLS);
    float var = (tot_q - tot_s*mu) * (1.0f/(CLS-1));
    var = fmaxf(var, 0.0f);
    const float inv_sigma = 1.0f / fmaxf(sqrtf(var), 1e-6f);

    // ---- pass 0 scan: thread t owns bins [8t,8t+8) ----
    unsigned kr = KSEL;
    {
        uint4 x0 = *(const uint4*)&h0[tid*8];
        uint4 x1 = *(const uint4*)&h0[tid*8 + 4];
        unsigned c[8] = { x0.x, x0.y, x0.z, x0.w, x1.x, x1.y, x1.z, x1.w };
        unsigned sfx[9]; sfx[8] = 0;
        #pragma unroll
        for (int j = 7; j >= 0; --j) sfx[j] = sfx[j+1] + c[j];
        const unsigned tot = sfx[0];
        unsigned s = tot;
        #pragma unroll
        for (int off = 1; off < 64; off <<= 1) {
            unsigned t = __shfl_down(s, off);
            if (lane + off < 64) s += t;
        }
        if (lane == 0) s_wt[wv] = s;
        __syncthreads();                             // B2
        unsigned addhi = 0;
        #pragma unroll
        for (int w2 = 0; w2 < 4; ++w2) if (w2 > wv) addhi += s_wt[w2];
        const unsigned Sx = (s - tot) + addhi;
        if (Sx < kr && kr <= Sx + tot) {
            #pragma unroll
            for (int j = 0; j < 8; ++j)
                if (Sx + sfx[j] >= kr && Sx + sfx[j+1] < kr) {
                    s_bc[0] = (unsigned)(tid*8 + j);
                    s_bc[1] = Sx + sfx[j+1];
                    s_bc[2] = c[j];
                }
        }
        __syncthreads();                             // B3
        kr -= s_bc[1];
    }
    const unsigned bin = s_bc[0];
    unsigned cnt_eq = s_bc[2];

    // ---- gather boundary-bin candidates: key=(u<<12)|(4095-idx), distinct ----
    {
        unsigned cmask = 0, lc = 0;
        #pragma unroll
        for (int ii = 0; ii < 16; ++ii) {
            bool cnd = ((__float_as_uint(sc[ii]) >> 20) == bin);
            cmask |= ((unsigned)cnd) << ii;
            lc += (unsigned)cnd;
        }
        unsigned inc = lc;
        #pragma unroll
        for (int off = 1; off < 64; off <<= 1) {
            unsigned t = __shfl_up(inc, off);
            if (lane >= off) inc += t;
        }
        const unsigned wtot = __shfl(inc, 63);
        unsigned wbase = 0;
        if (lane == 0) wbase = atomicAdd(s_cnt, wtot);
        wbase = __shfl(wbase, 0);
        unsigned p = wbase + (inc - lc);
        #pragma unroll
        for (int ii = 0; ii < 16; ++ii) {
            if ((cmask >> ii) & 1u) {
                unsigned u = __float_as_uint(sc[ii]);
                unsigned idx = (unsigned)((ii >> 2)*1024 + tid*4 + (ii & 3));
                if (p < 512u) cand[p] = (u << 12) | (4095u - idx);
                ++p;
            }
        }
    }
    __syncthreads();                                 // B4
    const unsigned cnt = *s_cnt;
    const bool cand_mode = (cnt <= 512u);

    float thr = 0.f; bool tie_rare = false;
    if (cand_mode) {
        // ---- cooperative rank: thread handles cand slots tid, tid+256 ----
        #pragma unroll
        for (int rpt = 0; rpt < 2; ++rpt) {
            const unsigned slot = (unsigned)tid + (unsigned)rpt*256u;
            if (slot < cnt) {
                const unsigned my = cand[slot];
                unsigned rank = 0;
                const uint4* c4 = (const uint4*)cand;
                const unsigned nq = (cnt + 3u) >> 2;
                for (unsigned q = 0; q < nq; ++q) {  // same-address broadcast reads
                    uint4 v = c4[q];
                    rank += (unsigned)(v.x > my) + (unsigned)(v.y > my)
                          + (unsigned)(v.z > my) + (unsigned)(v.w > my);
                }
                if (rank == kr - 1u) s_bc[0] = my;   // unique: keys distinct
            }
        }
    } else {
        // ---- rare fallback (cnt>512): radix chain + stable tie ranking ----
        unsigned prefix = bin << 20;
        {
            unsigned* hz = (unsigned*)(lds + 5120);  // zero h1/h2/h3 (h0 dead)
            #pragma unroll
            for (int m = 0; m < 3; ++m) { int ix = m*TPB + tid; if (ix < 584) hz[ix] = 0u; }
        }
        __syncthreads();
        radix_small<12, 8, 4>(sc, h1, lane, prefix, kr, cnt_eq);
        radix_small< 4, 8, 4>(sc, h2, lane, prefix, kr, cnt_eq);
        radix_small< 0, 4, 1>(sc, h3, lane, prefix, kr, cnt_eq);
        thr = __uint_as_float(prefix);
        tie_rare = (cnt_eq != kr);
        if (tie_rare) {
            #pragma unroll
            for (int i = 0; i < 4; ++i)
                #pragma unroll
                for (int c2 = 0; c2 < 4; ++c2)
                    s_flag[i*1024 + tid*4 + c2] = (sc[i*4+c2] == thr) ? 1 : 0;
            __syncthreads();
            unsigned lc = 0;
            unsigned char mf[16];
            #pragma unroll
            for (int m = 0; m < 16; ++m) { mf[m] = s_flag[tid*16 + m]; lc += mf[m]; }
            s_suf[tid] = lc;
            __syncthreads();
            #pragma unroll
            for (int off = 1; off < 256; off <<= 1) {
                unsigned w = s_suf[tid] + ((tid >= off) ? s_suf[tid - off] : 0u);
                __syncthreads();
                s_suf[tid] = w;
                __syncthreads();
            }
            unsigned r2 = s_suf[tid] - lc;
            #pragma unroll
            for (int m = 0; m < 16; ++m) {
                if (mf[m]) { s_flag[tid*16 + m] = (r2 < kr) ? 2 : 0; ++r2; }
            }
        }
    }
    __syncthreads();                                 // B5: Kth / flags visible
    const unsigned long long Kth64 =
        ((unsigned long long)bin << 32) | (unsigned long long)s_bc[0];

    // ---- gate + store: sigmoid via exp2+raw rcp; hard via one u64 compare ----
    const float A  = -inv_sigma * 1.44269504f;       // exp(-z) = 2^(s*A + Bc)
    const float Bc = -mu * A;
    const unsigned rbase = 1023u - 4u*(unsigned)tid; // 4095-idx = rbase+(3-i)*1024-c2
    #pragma unroll
    for (int i = 0; i < 4; ++i) {
        const float tkc[4] = { tv[i].x, tv[i].y, tv[i].z, tv[i].w };
        f32x4 rv;
        #pragma unroll
        for (int c2 = 0; c2 < 4; ++c2) {
            const float s = sc[i*4+c2];
            const float e2 = __builtin_amdgcn_exp2f(fmaf(s, A, Bc));
            const float soft = __builtin_amdgcn_rcpf(1.0f + e2);
            const unsigned u = __float_as_uint(s);
            bool hard;
            if (cand_mode) {
                const unsigned long long key =
                    ((unsigned long long)(u >> 20) << 32)
                    | (unsigned long long)((u << 12) | (rbase + (3u-(unsigned)i)*1024u - (unsigned)c2));
                hard = (key >= Kth64);
            } else if (tie_rare) {
                hard = (s > thr) || ((s == thr) && (s_flag[i*1024 + tid*4 + c2] == 2));
            } else {
                hard = (s >= thr);
            }
            rv[c2] = tkc[c2] * (hard ? 1.0f : soft);
        }
        __builtin_nontemporal_store(rv, &o4[i*TPB + tid]);
    }
}

extern "C" void kernel_launch(void* const* d_in, const int* in_sizes, int n_in,
                              void* d_out, int out_size, void* d_ws, size_t ws_size,
                              hipStream_t stream) {
    const float* token = (const float*)d_in[0];
    const float* proxy = (const float*)d_in[1];
    float* outp = (float*)d_out;
    const int B = in_sizes[0] / CLS;
    hipLaunchKernelGGL(proxy_gate_kernel, dim3(B), dim3(TPB), 0, stream,
                       token, proxy, outp);
}